// Round 5
// baseline (1097.617 us; speedup 1.0000x reference)
//
#include <hip/hip_runtime.h>
#include <hip/hip_bf16.h>

typedef __attribute__((ext_vector_type(8))) short bf16x8; // 8 bf16 in 4 VGPRs
typedef __attribute__((ext_vector_type(4))) float f32x4;

#define MFMA16(a, b, c) __builtin_amdgcn_mfma_f32_16x16x32_bf16(a, b, c, 0, 0, 0)

static constexpr int S  = 4096;
static constexpr int Dm = 512;
static constexpr int Hh = 256;
static constexpr int Bb = 4;

// Swizzled LDS index helpers (bf16 units; 16B slot granularity).
__device__ __forceinline__ int kidx(int r, int c) { return r * 256 + (c ^ ((r & 7) << 3)); }
__device__ __forceinline__ int vidx(int r, int c) { return r * 64  + (c ^ ((r & 7) << 3)); }
__device__ __forceinline__ int pidx(int r, int c) { return r * 64  + (c ^ ((r & 7) << 3)); }

// ---------------------------------------------------------------------------
// Projection GEMM with depth-1 register prefetch + LDS double-buffer (kept).
// ---------------------------------------------------------------------------
__global__ __launch_bounds__(256) void proj_kernel(
    const float* __restrict__ X,
    const float* __restrict__ W,
    const float* __restrict__ bias,
    __hip_bfloat16* __restrict__ out,
    int N, float scale, int transpose_out)
{
    __shared__ __hip_bfloat16 a_lds[2][64][32];
    __shared__ __hip_bfloat16 w_lds[2][64][32];

    const int tid  = threadIdx.x;
    const int lane = tid & 63;
    const int wave = tid >> 6;
    const int lr   = lane & 15;
    const int lg   = lane >> 4;
    const int m0   = blockIdx.y * 64;
    const int n0   = blockIdx.x * 64;

    const int arow = tid >> 2, aoff = (tid & 3) * 8;
    const int wkk  = tid >> 3, wnoff = (tid & 7) * 8;
    const float* asrc = X + (size_t)(m0 + arow) * 512 + aoff;
    const float* wsrc = W + (size_t)wkk * N + n0 + wnoff;

    f32x4 acc[4];
    #pragma unroll
    for (int n = 0; n < 4; ++n) acc[n] = (f32x4){0.f, 0.f, 0.f, 0.f};

    {
        float ar[8], wr[8];
        #pragma unroll
        for (int j = 0; j < 8; ++j) { ar[j] = asrc[j]; wr[j] = wsrc[j]; }
        #pragma unroll
        for (int j = 0; j < 8; ++j) a_lds[0][arow][aoff + j] = __float2bfloat16(ar[j]);
        #pragma unroll
        for (int j = 0; j < 8; ++j) w_lds[0][wnoff + j][wkk] = __float2bfloat16(wr[j]);
    }
    __syncthreads();

    int cur = 0;
    for (int k0 = 0; k0 < 512; k0 += 32) {
        float ar[8], wr[8];
        if (k0 < 480) {
            #pragma unroll
            for (int j = 0; j < 8; ++j) ar[j] = asrc[k0 + 32 + j];
            #pragma unroll
            for (int j = 0; j < 8; ++j) wr[j] = wsrc[(size_t)(k0 + 32) * N + j];
        }
        bf16x8 af = *(const bf16x8*)&a_lds[cur][wave * 16 + lr][lg * 8];
        __builtin_amdgcn_s_setprio(1);
        #pragma unroll
        for (int n = 0; n < 4; ++n) {
            bf16x8 bfr = *(const bf16x8*)&w_lds[cur][n * 16 + lr][lg * 8];
            acc[n] = MFMA16(af, bfr, acc[n]);
        }
        __builtin_amdgcn_s_setprio(0);
        if (k0 < 480) {
            #pragma unroll
            for (int j = 0; j < 8; ++j) a_lds[cur ^ 1][arow][aoff + j] = __float2bfloat16(ar[j]);
            #pragma unroll
            for (int j = 0; j < 8; ++j) w_lds[cur ^ 1][wnoff + j][wkk] = __float2bfloat16(wr[j]);
        }
        __syncthreads();
        cur ^= 1;
    }

    #pragma unroll
    for (int n = 0; n < 4; ++n) {
        int col = n0 + n * 16 + lr;
        float bia = bias[col];
        #pragma unroll
        for (int r = 0; r < 4; ++r) {
            int row = m0 + wave * 16 + lg * 4 + r;
            float val = (acc[n][r] + bia) * scale;
            if (!transpose_out) {
                out[(size_t)row * N + col] = __float2bfloat16(val);
            } else {
                int bidx = row >> 12, s = row & 4095;
                out[((size_t)bidx * N + col) * S + s] = __float2bfloat16(val);
            }
        }
    }
}

// ---------------------------------------------------------------------------
// Attention v5 = R2's fused structure at 72 KB LDS -> 2 blocks/CU.
// 512 threads / 8 waves per (batch, 64 q-rows). Wave (qg=w>>1) owns q-rows
// 16qg..+16; (half=w&1) owns kv-cols 32*half..+32 for QK^T.
// Pass 1: no-max softmax row sums (1 stage + QK per kt).
// Pass 2: QK -> softmax+fmf -> attn store + p_lds; PV in two D-phases
// (stage VT d[0,256) -> PV-A; stage VT d[256,512) -> PV-B), wave w owning
// d-slices [32w,32w+32) and [256+32w,...).
// ---------------------------------------------------------------------------
__global__ __launch_bounds__(512, 4) void attn_kernel(
    const __hip_bfloat16* __restrict__ Q,   // [B][S][H], 1/sqrt(H) pre-applied
    const __hip_bfloat16* __restrict__ K,   // [B][S][H]
    const __hip_bfloat16* __restrict__ VT,  // [B][D][S]
    float* __restrict__ out,                // [B][S][D]
    float* __restrict__ attn)               // [B][S][S]
{
    __shared__ __align__(16) char smem[73856];
    __hip_bfloat16* k_lds  = (__hip_bfloat16*)smem;            // [64*256] 32 KB
    __hip_bfloat16* vt_lds = (__hip_bfloat16*)(smem + 32768);  // [256*64] 32 KB
    __hip_bfloat16* p_lds  = (__hip_bfloat16*)(smem + 65536);  // [64*64]   8 KB
    float* stats_lds       = (float*)(smem + 73728);           // [2][4][16]

    const int tid  = threadIdx.x;
    const int lane = tid & 63;
    const int w    = tid >> 6;   // 0..7
    const int lr   = lane & 15;
    const int lg   = lane >> 4;
    const int qg   = w >> 1;     // 0..3
    const int half = w & 1;      // 0..1
    const int b    = blockIdx.y;
    const int q0   = blockIdx.x * 64;

    const __hip_bfloat16* Qb  = Q  + ((size_t)b * S + q0) * Hh;
    const __hip_bfloat16* Kb  = K  + (size_t)b * S * Hh;
    const __hip_bfloat16* VTb = VT + (size_t)b * Dm * S;

    // K staging: wave covers whole 512B rows (conflict-free writes):
    // lane -> slot sl=lane&31, row-half rh=lane>>5; iter c0: row = w*8+c0*2+rh.
    const int ksl = lane & 31, krh = lane >> 5;
    // VT staging: 64 rows x 8 slots per pass; thread -> row tid>>3, slot tid&7.
    const int vrb = tid >> 3, vcb = (tid & 7) * 8;

    bf16x8 qf[8];
    #pragma unroll
    for (int h = 0; h < 8; ++h)
        qf[h] = *(const bf16x8*)&Qb[(size_t)(qg * 16 + lr) * Hh + h * 32 + lg * 8];

    // ---------------- pass 1: row sums of exp(s) ----------------
    float lsum[4] = {0.f, 0.f, 0.f, 0.f};
    for (int kt = 0; kt < 64; ++kt) {
        __syncthreads();
        #pragma unroll
        for (int c0 = 0; c0 < 4; ++c0) {
            int row = w * 8 + c0 * 2 + krh;
            *(uint4*)&k_lds[kidx(row, ksl * 8)] =
                *(const uint4*)&Kb[(size_t)(kt * 64 + row) * Hh + ksl * 8];
        }
        __syncthreads();

        f32x4 acc[2];
        #pragma unroll
        for (int nn = 0; nn < 2; ++nn) acc[nn] = (f32x4){0.f, 0.f, 0.f, 0.f};
        __builtin_amdgcn_s_setprio(1);
        #pragma unroll
        for (int nn = 0; nn < 2; ++nn) {
            int n = half * 2 + nn;
            #pragma unroll
            for (int h = 0; h < 8; ++h) {
                bf16x8 kf = *(const bf16x8*)&k_lds[kidx(n * 16 + lr, h * 32 + lg * 8)];
                acc[nn] = MFMA16(qf[h], kf, acc[nn]);
            }
        }
        __builtin_amdgcn_s_setprio(0);
        #pragma unroll
        for (int r = 0; r < 4; ++r)
            lsum[r] += __expf(acc[0][r]) + __expf(acc[1][r]);
    }

    // reduce across the 16 lr lanes; merge the two kv-halves via LDS
    #pragma unroll
    for (int r = 0; r < 4; ++r)
        #pragma unroll
        for (int m = 1; m < 16; m <<= 1) lsum[r] += __shfl_xor(lsum[r], m);
    if (lr == 0) {
        #pragma unroll
        for (int r = 0; r < 4; ++r)
            stats_lds[half * 64 + qg * 16 + lg * 4 + r] = lsum[r];
    }
    __syncthreads();
    float inv_l[4];
    #pragma unroll
    for (int r = 0; r < 4; ++r)
        inv_l[r] = 1.0f / (lsum[r] + stats_lds[(half ^ 1) * 64 + qg * 16 + lg * 4 + r]);

    f32x4 oacc[4][4];   // [qt][dt: 0,1=phase A, 2,3=phase B]
    #pragma unroll
    for (int qt = 0; qt < 4; ++qt)
        #pragma unroll
        for (int dt = 0; dt < 4; ++dt) oacc[qt][dt] = (f32x4){0.f, 0.f, 0.f, 0.f};

    // ---------------- pass 2: attn write + PV (two D-phases) ----------------
    for (int kt = 0; kt < 64; ++kt) {
        __syncthreads();  // prev PV-B done: k/vt/p free
        // stage K(kt) + VT phase A (d in [0,256))
        #pragma unroll
        for (int c0 = 0; c0 < 4; ++c0) {
            int row = w * 8 + c0 * 2 + krh;
            *(uint4*)&k_lds[kidx(row, ksl * 8)] =
                *(const uint4*)&Kb[(size_t)(kt * 64 + row) * Hh + ksl * 8];
        }
        #pragma unroll
        for (int j = 0; j < 4; ++j) {
            int row = j * 64 + vrb;   // = global d row
            *(uint4*)&vt_lds[vidx(row, vcb)] =
                *(const uint4*)&VTb[(size_t)row * S + kt * 64 + vcb];
        }
        __syncthreads();

        // QK^T
        f32x4 acc[2];
        #pragma unroll
        for (int nn = 0; nn < 2; ++nn) acc[nn] = (f32x4){0.f, 0.f, 0.f, 0.f};
        __builtin_amdgcn_s_setprio(1);
        #pragma unroll
        for (int nn = 0; nn < 2; ++nn) {
            int n = half * 2 + nn;
            #pragma unroll
            for (int h = 0; h < 8; ++h) {
                bf16x8 kf = *(const bf16x8*)&k_lds[kidx(n * 16 + lr, h * 32 + lg * 8)];
                acc[nn] = MFMA16(qf[h], kf, acc[nn]);
            }
        }
        __builtin_amdgcn_s_setprio(0);

        // softmax + fuzzy clamp; attn store (fp32) + P (bf16, swizzled)
        #pragma unroll
        for (int nn = 0; nn < 2; ++nn)
            #pragma unroll
            for (int r = 0; r < 4; ++r) {
                float p = __expf(acc[nn][r]) * inv_l[r];
                float f = fmaxf(fminf(p, 1.0f - p) * (1.0f / 0.3f), 0.0f);
                int row_l = qg * 16 + lg * 4 + r;
                int col_l = (half * 2 + nn) * 16 + lr;
                attn[((size_t)(b * S + q0 + row_l)) * S + kt * 64 + col_l] = f;
                p_lds[pidx(row_l, col_l)] = __float2bfloat16(f);
            }
        __syncthreads();  // p_lds visible

        // PV phase A: wave w owns d-slice [32w, 32w+32)
        bf16x8 pf[4][2];
        #pragma unroll
        for (int qt = 0; qt < 4; ++qt)
            #pragma unroll
            for (int ks = 0; ks < 2; ++ks)
                pf[qt][ks] = *(const bf16x8*)&p_lds[pidx(qt * 16 + lr, ks * 32 + lg * 8)];
        __builtin_amdgcn_s_setprio(1);
        #pragma unroll
        for (int dt = 0; dt < 2; ++dt)
            #pragma unroll
            for (int ks = 0; ks < 2; ++ks) {
                bf16x8 vf = *(const bf16x8*)&vt_lds[vidx(w * 32 + dt * 16 + lr, ks * 32 + lg * 8)];
                #pragma unroll
                for (int qt = 0; qt < 4; ++qt)
                    oacc[qt][dt] = MFMA16(pf[qt][ks], vf, oacc[qt][dt]);
            }
        __builtin_amdgcn_s_setprio(0);
        __syncthreads();  // PV-A done -> vt_lds reusable

        // stage VT phase B (d in [256,512))
        #pragma unroll
        for (int j = 0; j < 4; ++j) {
            int row = j * 64 + vrb;
            *(uint4*)&vt_lds[vidx(row, vcb)] =
                *(const uint4*)&VTb[(size_t)(256 + row) * S + kt * 64 + vcb];
        }
        __syncthreads();

        // PV phase B: wave w owns d-slice [256+32w, 256+32w+32)
        __builtin_amdgcn_s_setprio(1);
        #pragma unroll
        for (int dt = 0; dt < 2; ++dt)
            #pragma unroll
            for (int ks = 0; ks < 2; ++ks) {
                bf16x8 vf = *(const bf16x8*)&vt_lds[vidx(w * 32 + dt * 16 + lr, ks * 32 + lg * 8)];
                #pragma unroll
                for (int qt = 0; qt < 4; ++qt)
                    oacc[qt][dt + 2] = MFMA16(pf[qt][ks], vf, oacc[qt][dt + 2]);
            }
        __builtin_amdgcn_s_setprio(0);
    }

    // epilogue: out[B][S][D] fp32
    #pragma unroll
    for (int qt = 0; qt < 4; ++qt)
        #pragma unroll
        for (int dt = 0; dt < 4; ++dt) {
            int col = (dt < 2 ? 0 : 256) + w * 32 + (dt & 1) * 16 + lr;
            #pragma unroll
            for (int r = 0; r < 4; ++r) {
                int row = q0 + qt * 16 + lg * 4 + r;
                out[((size_t)(b * S + row)) * Dm + col] = oacc[qt][dt][r];
            }
        }
}

// ---------------------------------------------------------------------------
extern "C" void kernel_launch(void* const* d_in, const int* in_sizes, int n_in,
                              void* d_out, int out_size, void* d_ws, size_t ws_size,
                              hipStream_t stream) {
    const float* x  = (const float*)d_in[0];
    const float* Wq = (const float*)d_in[1];
    const float* bq = (const float*)d_in[2];
    const float* Wk = (const float*)d_in[3];
    const float* bk = (const float*)d_in[4];
    const float* Wv = (const float*)d_in[5];
    const float* bv = (const float*)d_in[6];

    float* out  = (float*)d_out;                      // [4,4096,512]
    float* attn = out + (size_t)Bb * S * Dm;          // [4,4096,4096]

    __hip_bfloat16* q_ws  = (__hip_bfloat16*)d_ws;              // [B][S][H]
    __hip_bfloat16* k_ws  = q_ws + (size_t)Bb * S * Hh;         // [B][S][H]
    __hip_bfloat16* vt_ws = k_ws + (size_t)Bb * S * Hh;         // [B][D][S]

    const float scale = 0.0625f;  // 1/sqrt(256)

    proj_kernel<<<dim3(Hh / 64, (Bb * S) / 64), 256, 0, stream>>>(x, Wq, bq, q_ws, Hh, scale, 0);
    proj_kernel<<<dim3(Hh / 64, (Bb * S) / 64), 256, 0, stream>>>(x, Wk, bk, k_ws, Hh, 1.0f, 0);
    proj_kernel<<<dim3(Dm / 64, (Bb * S) / 64), 256, 0, stream>>>(x, Wv, bv, vt_ws, Dm, 1.0f, 1);

    attn_kernel<<<dim3(S / 64, Bb), 512, 0, stream>>>(q_ws, k_ws, vt_ws, out, attn);
}

// Round 6
// 916.239 us; speedup vs baseline: 1.1980x; 1.1980x over previous
//
#include <hip/hip_runtime.h>
#include <hip/hip_bf16.h>

typedef __attribute__((ext_vector_type(8))) short bf16x8; // 8 bf16 in 4 VGPRs
typedef __attribute__((ext_vector_type(4))) float f32x4;

#define MFMA16(a, b, c) __builtin_amdgcn_mfma_f32_16x16x32_bf16(a, b, c, 0, 0, 0)

static constexpr int S  = 4096;
static constexpr int Dm = 512;
static constexpr int Hh = 256;
static constexpr int Bb = 4;

// Swizzled LDS index helpers (bf16 element units; 16B slot granularity).
// idx256: 256-elem-wide rows (K tiles); idx128: 128-elem-wide rows (VT / P).
__device__ __forceinline__ int idx256(int r, int c) { return r * 256 + (c ^ ((r & 7) << 3)); }
__device__ __forceinline__ int idx128(int r, int c) { return r * 128 + (c ^ ((r & 7) << 3)); }

// ---------------------------------------------------------------------------
// Projection GEMM with depth-1 register prefetch + LDS double-buffer (kept).
// ---------------------------------------------------------------------------
__global__ __launch_bounds__(256) void proj_kernel(
    const float* __restrict__ X,
    const float* __restrict__ W,
    const float* __restrict__ bias,
    __hip_bfloat16* __restrict__ out,
    int N, float scale, int transpose_out)
{
    __shared__ __hip_bfloat16 a_lds[2][64][32];
    __shared__ __hip_bfloat16 w_lds[2][64][32];

    const int tid  = threadIdx.x;
    const int lane = tid & 63;
    const int wave = tid >> 6;
    const int lr   = lane & 15;
    const int lg   = lane >> 4;
    const int m0   = blockIdx.y * 64;
    const int n0   = blockIdx.x * 64;

    const int arow = tid >> 2, aoff = (tid & 3) * 8;
    const int wkk  = tid >> 3, wnoff = (tid & 7) * 8;
    const float* asrc = X + (size_t)(m0 + arow) * 512 + aoff;
    const float* wsrc = W + (size_t)wkk * N + n0 + wnoff;

    f32x4 acc[4];
    #pragma unroll
    for (int n = 0; n < 4; ++n) acc[n] = (f32x4){0.f, 0.f, 0.f, 0.f};

    {
        float ar[8], wr[8];
        #pragma unroll
        for (int j = 0; j < 8; ++j) { ar[j] = asrc[j]; wr[j] = wsrc[j]; }
        #pragma unroll
        for (int j = 0; j < 8; ++j) a_lds[0][arow][aoff + j] = __float2bfloat16(ar[j]);
        #pragma unroll
        for (int j = 0; j < 8; ++j) w_lds[0][wnoff + j][wkk] = __float2bfloat16(wr[j]);
    }
    __syncthreads();

    int cur = 0;
    for (int k0 = 0; k0 < 512; k0 += 32) {
        float ar[8], wr[8];
        if (k0 < 480) {
            #pragma unroll
            for (int j = 0; j < 8; ++j) ar[j] = asrc[k0 + 32 + j];
            #pragma unroll
            for (int j = 0; j < 8; ++j) wr[j] = wsrc[(size_t)(k0 + 32) * N + j];
        }
        bf16x8 af = *(const bf16x8*)&a_lds[cur][wave * 16 + lr][lg * 8];
        __builtin_amdgcn_s_setprio(1);
        #pragma unroll
        for (int n = 0; n < 4; ++n) {
            bf16x8 bfr = *(const bf16x8*)&w_lds[cur][n * 16 + lr][lg * 8];
            acc[n] = MFMA16(af, bfr, acc[n]);
        }
        __builtin_amdgcn_s_setprio(0);
        if (k0 < 480) {
            #pragma unroll
            for (int j = 0; j < 8; ++j) a_lds[cur ^ 1][arow][aoff + j] = __float2bfloat16(ar[j]);
            #pragma unroll
            for (int j = 0; j < 8; ++j) w_lds[cur ^ 1][wnoff + j][wkk] = __float2bfloat16(wr[j]);
        }
        __syncthreads();
        cur ^= 1;
    }

    #pragma unroll
    for (int n = 0; n < 4; ++n) {
        int col = n0 + n * 16 + lr;
        float bia = bias[col];
        #pragma unroll
        for (int r = 0; r < 4; ++r) {
            int row = m0 + wave * 16 + lg * 4 + r;
            float val = (acc[n][r] + bia) * scale;
            if (!transpose_out) {
                out[(size_t)row * N + col] = __float2bfloat16(val);
            } else {
                int bidx = row >> 12, s = row & 4095;
                out[((size_t)bidx * N + col) * S + s] = __float2bfloat16(val);
            }
        }
    }
}

// ---------------------------------------------------------------------------
// Attention v6: fused, 32-row q-blocks -> grid (128,4) = 512 blocks, 2/CU.
// 512 threads / 8 waves. Wave w: qg = w>>2 (0..1) owns q-rows [16qg,16qg+16);
// half = w&3 (0..3) owns kv-cols [16*half, +16) of each 64-col kv tile.
// LDS: 64 KB union "region" + 8 KB P + stats = 72.5 KB -> 2 blocks/CU.
// Pass 1: K double-buffered in region, 1 barrier/kt, no-max row sums.
// Pass 2 (2 kt per step): region holds K-pair -> QK both tiles -> softmax ->
//   attn store + P[32][128]; then region holds VT d[0,256) -> PV-A;
//   then VT d[256,512) -> PV-B (pf reused from registers).
// ---------------------------------------------------------------------------
__global__ __launch_bounds__(512, 4) void attn_kernel(
    const __hip_bfloat16* __restrict__ Q,   // [B][S][H], 1/sqrt(H) pre-applied
    const __hip_bfloat16* __restrict__ K,   // [B][S][H]
    const __hip_bfloat16* __restrict__ VT,  // [B][D][S]
    float* __restrict__ out,                // [B][S][D]
    float* __restrict__ attn)               // [B][S][S]
{
    __shared__ __align__(16) char smem[74240];
    __hip_bfloat16* region = (__hip_bfloat16*)smem;            // 65536 B union
    __hip_bfloat16* p_lds  = (__hip_bfloat16*)(smem + 65536);  // [32][128] 8 KB
    float* stats_lds       = (float*)(smem + 73728);           // [4][2][16]

    const int tid  = threadIdx.x;
    const int lane = tid & 63;
    const int w    = tid >> 6;   // 0..7
    const int lr   = lane & 15;
    const int lg   = lane >> 4;
    const int qg   = w >> 2;     // 0..1
    const int half = w & 3;      // 0..3
    const int b    = blockIdx.y;
    const int q0   = blockIdx.x * 32;

    const __hip_bfloat16* Qb  = Q  + ((size_t)b * S + q0) * Hh;
    const __hip_bfloat16* Kb  = K  + (size_t)b * S * Hh;
    const __hip_bfloat16* VTb = VT + (size_t)b * Dm * S;

    // Q fragments: this wave's 16 q-rows over H=256 (8 k-steps).
    bf16x8 qf[8];
    #pragma unroll
    for (int h = 0; h < 8; ++h)
        qf[h] = *(const bf16x8*)&Qb[(size_t)(qg * 16 + lr) * Hh + h * 32 + lg * 8];

    // ---------------- pass 1: no-max row sums of exp(s), K dbuf ----------------
    {   // prologue: K(0) -> buf 0
        #pragma unroll
        for (int j = 0; j < 4; ++j) {
            int sid = j * 512 + tid, row = sid >> 5, sl = sid & 31;
            *(uint4*)&region[idx256(row, sl * 8)] =
                *(const uint4*)&Kb[(size_t)row * Hh + sl * 8];
        }
    }
    __syncthreads();

    float lsum[4] = {0.f, 0.f, 0.f, 0.f};
    for (int kt = 0; kt < 64; ++kt) {
        const int buf = (kt & 1) * 16384;
        f32x4 acc = (f32x4){0.f, 0.f, 0.f, 0.f};
        __builtin_amdgcn_s_setprio(1);
        #pragma unroll
        for (int h = 0; h < 8; ++h) {
            bf16x8 kf = *(const bf16x8*)&region[buf + idx256(half * 16 + lr, h * 32 + lg * 8)];
            acc = MFMA16(qf[h], kf, acc);
        }
        __builtin_amdgcn_s_setprio(0);
        if (kt < 63) {  // stage K(kt+1) into other buffer (after compute reads issued)
            #pragma unroll
            for (int j = 0; j < 4; ++j) {
                int sid = j * 512 + tid, row = sid >> 5, sl = sid & 31;
                *(uint4*)&region[(buf ^ 16384) + idx256(row, sl * 8)] =
                    *(const uint4*)&Kb[(size_t)((kt + 1) * 64 + row) * Hh + sl * 8];
            }
        }
        #pragma unroll
        for (int r = 0; r < 4; ++r) lsum[r] += __expf(acc[r]);
        __syncthreads();
    }

    // reduce over 16 lr lanes; merge the 4 kv-quarters via LDS
    #pragma unroll
    for (int r = 0; r < 4; ++r)
        #pragma unroll
        for (int m = 1; m < 16; m <<= 1) lsum[r] += __shfl_xor(lsum[r], m);
    if (lr == 0) {
        #pragma unroll
        for (int r = 0; r < 4; ++r)
            stats_lds[half * 32 + qg * 16 + lg * 4 + r] = lsum[r];
    }
    __syncthreads();
    float inv_l[4];
    #pragma unroll
    for (int r = 0; r < 4; ++r) {
        float t = 0.f;
        #pragma unroll
        for (int h2 = 0; h2 < 4; ++h2) t += stats_lds[h2 * 32 + qg * 16 + lg * 4 + r];
        inv_l[r] = 1.0f / t;
    }

    f32x4 oacc[2][4];   // [qt][dt: 0,1 = d<256 ; 2,3 = d>=256]
    #pragma unroll
    for (int qt = 0; qt < 2; ++qt)
        #pragma unroll
        for (int dt = 0; dt < 4; ++dt) oacc[qt][dt] = (f32x4){0.f, 0.f, 0.f, 0.f};

    // ---------------- pass 2: 2 kv-tiles per macro-step ----------------
    for (int kt2 = 0; kt2 < 32; ++kt2) {
        __syncthreads();  // b0: prev PV-B reads done; region free
        // stage K pair [128 kv][256 H]
        #pragma unroll
        for (int j = 0; j < 8; ++j) {
            int sid = j * 512 + tid, row = sid >> 5, sl = sid & 31;
            *(uint4*)&region[idx256(row, sl * 8)] =
                *(const uint4*)&Kb[(size_t)(kt2 * 128 + row) * Hh + sl * 8];
        }
        __syncthreads();  // b1

        // QK^T for both tiles
        f32x4 acc[2];
        #pragma unroll
        for (int t = 0; t < 2; ++t) acc[t] = (f32x4){0.f, 0.f, 0.f, 0.f};
        __builtin_amdgcn_s_setprio(1);
        #pragma unroll
        for (int t = 0; t < 2; ++t)
            #pragma unroll
            for (int h = 0; h < 8; ++h) {
                bf16x8 kf = *(const bf16x8*)&region[idx256(t * 64 + half * 16 + lr, h * 32 + lg * 8)];
                acc[t] = MFMA16(qf[h], kf, acc[t]);
            }
        __builtin_amdgcn_s_setprio(0);

        // softmax + fuzzy clamp; attn store (fp32) + P (bf16)
        #pragma unroll
        for (int t = 0; t < 2; ++t)
            #pragma unroll
            for (int r = 0; r < 4; ++r) {
                float p = __expf(acc[t][r]) * inv_l[r];
                float f = fmaxf(fminf(p, 1.0f - p) * (1.0f / 0.3f), 0.0f);
                int row_l = qg * 16 + lg * 4 + r;
                int col_l = t * 64 + half * 16 + lr;
                attn[((size_t)(b * S + q0 + row_l)) * S + kt2 * 128 + col_l] = f;
                p_lds[idx128(row_l, col_l)] = __float2bfloat16(f);
            }
        __syncthreads();  // b2: K reads done + p_lds ready

        // stage VT lower half: d rows [0,256), kv cols [kt2*128, +128)
        #pragma unroll
        for (int j = 0; j < 8; ++j) {
            int sid = j * 512 + tid, row = sid >> 4, sl = sid & 15;
            *(uint4*)&region[idx128(row, sl * 8)] =
                *(const uint4*)&VTb[(size_t)row * S + kt2 * 128 + sl * 8];
        }
        __syncthreads();  // b3

        // P fragments (reused for both PV phases)
        bf16x8 pf[2][4];
        #pragma unroll
        for (int qt = 0; qt < 2; ++qt)
            #pragma unroll
            for (int ks = 0; ks < 4; ++ks)
                pf[qt][ks] = *(const bf16x8*)&p_lds[idx128(qt * 16 + lr, ks * 32 + lg * 8)];

        // PV-A: wave w owns d-slice [32w, 32w+32)
        __builtin_amdgcn_s_setprio(1);
        #pragma unroll
        for (int dt = 0; dt < 2; ++dt)
            #pragma unroll
            for (int ks = 0; ks < 4; ++ks) {
                bf16x8 vf = *(const bf16x8*)&region[idx128(w * 32 + dt * 16 + lr, ks * 32 + lg * 8)];
                #pragma unroll
                for (int qt = 0; qt < 2; ++qt)
                    oacc[qt][dt] = MFMA16(pf[qt][ks], vf, oacc[qt][dt]);
            }
        __builtin_amdgcn_s_setprio(0);
        __syncthreads();  // b4: VT-lower reads done

        // stage VT upper half: d rows [256,512)
        #pragma unroll
        for (int j = 0; j < 8; ++j) {
            int sid = j * 512 + tid, row = sid >> 4, sl = sid & 15;
            *(uint4*)&region[idx128(row, sl * 8)] =
                *(const uint4*)&VTb[(size_t)(256 + row) * S + kt2 * 128 + sl * 8];
        }
        __syncthreads();  // b5

        // PV-B: wave w owns d-slice [256+32w, +32)
        __builtin_amdgcn_s_setprio(1);
        #pragma unroll
        for (int dt = 0; dt < 2; ++dt)
            #pragma unroll
            for (int ks = 0; ks < 4; ++ks) {
                bf16x8 vf = *(const bf16x8*)&region[idx128(w * 32 + dt * 16 + lr, ks * 32 + lg * 8)];
                #pragma unroll
                for (int qt = 0; qt < 2; ++qt)
                    oacc[qt][dt + 2] = MFMA16(pf[qt][ks], vf, oacc[qt][dt + 2]);
            }
        __builtin_amdgcn_s_setprio(0);
    }

    // epilogue: out[B][S][D] fp32
    #pragma unroll
    for (int qt = 0; qt < 2; ++qt)
        #pragma unroll
        for (int dt = 0; dt < 4; ++dt) {
            int col = (dt < 2 ? 0 : 256) + w * 32 + (dt & 1) * 16 + lr;
            #pragma unroll
            for (int r = 0; r < 4; ++r) {
                int row = q0 + qt * 16 + lg * 4 + r;
                out[((size_t)(b * S + row)) * Dm + col] = oacc[qt][dt][r];
            }
        }
}

// ---------------------------------------------------------------------------
extern "C" void kernel_launch(void* const* d_in, const int* in_sizes, int n_in,
                              void* d_out, int out_size, void* d_ws, size_t ws_size,
                              hipStream_t stream) {
    const float* x  = (const float*)d_in[0];
    const float* Wq = (const float*)d_in[1];
    const float* bq = (const float*)d_in[2];
    const float* Wk = (const float*)d_in[3];
    const float* bk = (const float*)d_in[4];
    const float* Wv = (const float*)d_in[5];
    const float* bv = (const float*)d_in[6];

    float* out  = (float*)d_out;                      // [4,4096,512]
    float* attn = out + (size_t)Bb * S * Dm;          // [4,4096,4096]

    __hip_bfloat16* q_ws  = (__hip_bfloat16*)d_ws;              // [B][S][H]
    __hip_bfloat16* k_ws  = q_ws + (size_t)Bb * S * Hh;         // [B][S][H]
    __hip_bfloat16* vt_ws = k_ws + (size_t)Bb * S * Hh;         // [B][D][S]

    const float scale = 0.0625f;  // 1/sqrt(256)

    proj_kernel<<<dim3(Hh / 64, (Bb * S) / 64), 256, 0, stream>>>(x, Wq, bq, q_ws, Hh, scale, 0);
    proj_kernel<<<dim3(Hh / 64, (Bb * S) / 64), 256, 0, stream>>>(x, Wk, bk, k_ws, Hh, 1.0f, 0);
    proj_kernel<<<dim3(Dm / 64, (Bb * S) / 64), 256, 0, stream>>>(x, Wv, bv, vt_ws, Dm, 1.0f, 1);

    attn_kernel<<<dim3(S / 32, Bb), 512, 0, stream>>>(q_ws, k_ws, vt_ws, out, attn);
}

// Round 7
// 598.764 us; speedup vs baseline: 1.8331x; 1.5302x over previous
//
#include <hip/hip_runtime.h>
#include <hip/hip_bf16.h>

typedef __attribute__((ext_vector_type(8))) short bf16x8; // 8 bf16 in 4 VGPRs
typedef __attribute__((ext_vector_type(4))) float f32x4;

#define MFMA16(a, b, c) __builtin_amdgcn_mfma_f32_16x16x32_bf16(a, b, c, 0, 0, 0)

static constexpr int S  = 4096;
static constexpr int Dm = 512;
static constexpr int Hh = 256;
static constexpr int Bb = 4;

// Swizzled LDS index helpers (bf16 element units; 16B slot granularity).
__device__ __forceinline__ int idx256(int r, int c) { return r * 256 + (c ^ ((r & 7) << 3)); }
__device__ __forceinline__ int idx64 (int r, int c) { return r * 64  + (c ^ ((r & 7) << 3)); }

// ---------------------------------------------------------------------------
// Projection GEMM with depth-1 register prefetch + LDS double-buffer (kept).
// ---------------------------------------------------------------------------
__global__ __launch_bounds__(256) void proj_kernel(
    const float* __restrict__ X,
    const float* __restrict__ W,
    const float* __restrict__ bias,
    __hip_bfloat16* __restrict__ out,
    int N, float scale, int transpose_out)
{
    __shared__ __hip_bfloat16 a_lds[2][64][32];
    __shared__ __hip_bfloat16 w_lds[2][64][32];

    const int tid  = threadIdx.x;
    const int lane = tid & 63;
    const int wave = tid >> 6;
    const int lr   = lane & 15;
    const int lg   = lane >> 4;
    const int m0   = blockIdx.y * 64;
    const int n0   = blockIdx.x * 64;

    const int arow = tid >> 2, aoff = (tid & 3) * 8;
    const int wkk  = tid >> 3, wnoff = (tid & 7) * 8;
    const float* asrc = X + (size_t)(m0 + arow) * 512 + aoff;
    const float* wsrc = W + (size_t)wkk * N + n0 + wnoff;

    f32x4 acc[4];
    #pragma unroll
    for (int n = 0; n < 4; ++n) acc[n] = (f32x4){0.f, 0.f, 0.f, 0.f};

    {
        float ar[8], wr[8];
        #pragma unroll
        for (int j = 0; j < 8; ++j) { ar[j] = asrc[j]; wr[j] = wsrc[j]; }
        #pragma unroll
        for (int j = 0; j < 8; ++j) a_lds[0][arow][aoff + j] = __float2bfloat16(ar[j]);
        #pragma unroll
        for (int j = 0; j < 8; ++j) w_lds[0][wnoff + j][wkk] = __float2bfloat16(wr[j]);
    }
    __syncthreads();

    int cur = 0;
    for (int k0 = 0; k0 < 512; k0 += 32) {
        float ar[8], wr[8];
        if (k0 < 480) {
            #pragma unroll
            for (int j = 0; j < 8; ++j) ar[j] = asrc[k0 + 32 + j];
            #pragma unroll
            for (int j = 0; j < 8; ++j) wr[j] = wsrc[(size_t)(k0 + 32) * N + j];
        }
        bf16x8 af = *(const bf16x8*)&a_lds[cur][wave * 16 + lr][lg * 8];
        __builtin_amdgcn_s_setprio(1);
        #pragma unroll
        for (int n = 0; n < 4; ++n) {
            bf16x8 bfr = *(const bf16x8*)&w_lds[cur][n * 16 + lr][lg * 8];
            acc[n] = MFMA16(af, bfr, acc[n]);
        }
        __builtin_amdgcn_s_setprio(0);
        if (k0 < 480) {
            #pragma unroll
            for (int j = 0; j < 8; ++j) a_lds[cur ^ 1][arow][aoff + j] = __float2bfloat16(ar[j]);
            #pragma unroll
            for (int j = 0; j < 8; ++j) w_lds[cur ^ 1][wnoff + j][wkk] = __float2bfloat16(wr[j]);
        }
        __syncthreads();
        cur ^= 1;
    }

    #pragma unroll
    for (int n = 0; n < 4; ++n) {
        int col = n0 + n * 16 + lr;
        float bia = bias[col];
        #pragma unroll
        for (int r = 0; r < 4; ++r) {
            int row = m0 + wave * 16 + lg * 4 + r;
            float val = (acc[n][r] + bia) * scale;
            if (!transpose_out) {
                out[(size_t)row * N + col] = __float2bfloat16(val);
            } else {
                int bidx = row >> 12, s = row & 4095;
                out[((size_t)bidx * N + col) * S + s] = __float2bfloat16(val);
            }
        }
    }
}

// ---------------------------------------------------------------------------
// lsum_kernel: QK^T + exp -> partial row sums only (no attn store).
// Flat grid 512, XCD-decoded: logical = (bx&7)*64 + (bx>>3);
//   b = logical>>7, kvh = (logical>>6)&1, q0 = (logical&63)*64.
// 512 threads / 8 waves: qg = w>>1 owns q-rows [16qg,+16); half = w&1 owns
// kv cols [32*half,+32) of each 64-col kt tile. 32 kt per block.
// LDS 32.5 KB -> 4 blocks/CU (wave-capped).
// ---------------------------------------------------------------------------
__global__ __launch_bounds__(512, 4) void lsum_kernel(
    const __hip_bfloat16* __restrict__ Q,   // [B][S][H], pre-scaled
    const __hip_bfloat16* __restrict__ K,   // [B][S][H]
    float* __restrict__ l_ws)               // [B][S][2] partial row sums
{
    __shared__ __hip_bfloat16 k_lds[64 * 256];  // 32 KB (swizzled)
    __shared__ float stats_lds[2][4][16];

    const int bx      = blockIdx.x;
    const int logical = (bx & 7) * 64 + (bx >> 3);
    const int b       = logical >> 7;
    const int kvh     = (logical >> 6) & 1;
    const int q0      = (logical & 63) * 64;

    const int tid  = threadIdx.x;
    const int lane = tid & 63;
    const int w    = tid >> 6;
    const int lr   = lane & 15;
    const int lg   = lane >> 4;
    const int qg   = w >> 1;
    const int half = w & 1;

    const __hip_bfloat16* Qb = Q + ((size_t)b * S + q0) * Hh;
    const __hip_bfloat16* Kb = K + (size_t)b * S * Hh;

    const int krow = tid >> 3, kcb = (tid & 7) * 8;

    bf16x8 qf[8];
    #pragma unroll
    for (int h = 0; h < 8; ++h)
        qf[h] = *(const bf16x8*)&Qb[(size_t)(qg * 16 + lr) * Hh + h * 32 + lg * 8];

    float lsum[4] = {0.f, 0.f, 0.f, 0.f};

    for (int kt = kvh * 32; kt < kvh * 32 + 32; ++kt) {
        uint4 kr[4];
        const __hip_bfloat16* src = Kb + (size_t)(kt * 64 + krow) * Hh + kcb;
        #pragma unroll
        for (int c0 = 0; c0 < 4; ++c0) kr[c0] = *(const uint4*)&src[c0 * 64];
        __syncthreads();  // previous tile's readers done
        #pragma unroll
        for (int c0 = 0; c0 < 4; ++c0)
            *(uint4*)&k_lds[idx256(krow, kcb + c0 * 64)] = kr[c0];
        __syncthreads();

        f32x4 acc[2];
        #pragma unroll
        for (int nn = 0; nn < 2; ++nn) acc[nn] = (f32x4){0.f, 0.f, 0.f, 0.f};
        __builtin_amdgcn_s_setprio(1);
        #pragma unroll
        for (int nn = 0; nn < 2; ++nn) {
            int n = half * 2 + nn;
            #pragma unroll
            for (int h = 0; h < 8; ++h) {
                bf16x8 kf = *(const bf16x8*)&k_lds[idx256(n * 16 + lr, h * 32 + lg * 8)];
                acc[nn] = MFMA16(qf[h], kf, acc[nn]);
            }
        }
        __builtin_amdgcn_s_setprio(0);
        #pragma unroll
        for (int r = 0; r < 4; ++r)
            lsum[r] += __expf(acc[0][r]) + __expf(acc[1][r]);
    }

    #pragma unroll
    for (int r = 0; r < 4; ++r)
        #pragma unroll
        for (int m = 1; m < 16; m <<= 1) lsum[r] += __shfl_xor(lsum[r], m);
    if (lr == 0) {
        #pragma unroll
        for (int r = 0; r < 4; ++r) stats_lds[half][qg][lg * 4 + r] = lsum[r];
    }
    __syncthreads();
    if (half == 0 && lr == 0) {
        #pragma unroll
        for (int r = 0; r < 4; ++r) {
            int row = q0 + qg * 16 + lg * 4 + r;
            l_ws[((size_t)(b * S + row)) * 2 + kvh] =
                lsum[r] + stats_lds[1][qg][lg * 4 + r];
        }
    }
}

// ---------------------------------------------------------------------------
// pv_kernel: uniform fused pass -> QK^T, f=fmf(exp*inv_l), attn store, PV.
// Flat grid 512, XCD-decoded: logical = (bx&7)*64 + (bx>>3);
//   b = logical>>7, q0 = (logical&127)*32.
// 512 threads / 8 waves; 32 q-rows. Per kt (64 total, 64 kv cols each):
//   stage K(32KB) -> QK (qg=w>>2, half=w&3) -> f + attn + P ->
//   stage VT d[0,256) -> PV-A -> stage VT d[256,512) -> PV-B.
// LDS = 32 KB union region + 4 KB P = 36.5 KB -> 4 blocks/CU.
// ---------------------------------------------------------------------------
__global__ __launch_bounds__(512, 4) void pv_kernel(
    const __hip_bfloat16* __restrict__ Q,   // [B][S][H], pre-scaled
    const __hip_bfloat16* __restrict__ K,   // [B][S][H]
    const __hip_bfloat16* __restrict__ VT,  // [B][D][S]
    const float* __restrict__ l_ws,         // [B][S][2]
    float* __restrict__ out,                // [B][S][D]
    float* __restrict__ attn)               // [B][S][S]
{
    __shared__ __align__(16) char smem[37888];
    __hip_bfloat16* region = (__hip_bfloat16*)smem;            // 32 KB union
    __hip_bfloat16* p_lds  = (__hip_bfloat16*)(smem + 32768);  // [32][64] 4 KB

    const int bx      = blockIdx.x;
    const int logical = (bx & 7) * 64 + (bx >> 3);
    const int b       = logical >> 7;
    const int q0      = (logical & 127) * 32;

    const int tid  = threadIdx.x;
    const int lane = tid & 63;
    const int w    = tid >> 6;   // 0..7
    const int lr   = lane & 15;
    const int lg   = lane >> 4;
    const int qg   = w >> 2;     // 0..1
    const int half = w & 3;      // 0..3
    const __hip_bfloat16* Qb  = Q  + ((size_t)b * S + q0) * Hh;
    const __hip_bfloat16* Kb  = K  + (size_t)b * S * Hh;
    const __hip_bfloat16* VTb = VT + (size_t)b * Dm * S;

    // Q fragments: wave's 16 q-rows over H=256.
    bf16x8 qf[8];
    #pragma unroll
    for (int h = 0; h < 8; ++h)
        qf[h] = *(const bf16x8*)&Qb[(size_t)(qg * 16 + lr) * Hh + h * 32 + lg * 8];

    // inv_l for this thread's 4 q-rows
    float inv_l[4];
    #pragma unroll
    for (int r = 0; r < 4; ++r) {
        int row = q0 + qg * 16 + lg * 4 + r;
        float2 lp = *(const float2*)&l_ws[((size_t)(b * S + row)) * 2];
        inv_l[r] = 1.0f / (lp.x + lp.y);
    }

    // staging maps
    const int krow = tid >> 3, kcb = (tid & 7) * 8;   // K [64][256]
    const int vrow = tid >> 3, vcb = (tid & 7) * 8;   // VT [256][64]: 4 rows/thread

    f32x4 oacc[2][4];   // [qt][dt: 0,1 = d<256 ; 2,3 = d>=256]
    #pragma unroll
    for (int qt = 0; qt < 2; ++qt)
        #pragma unroll
        for (int dt = 0; dt < 4; ++dt) oacc[qt][dt] = (f32x4){0.f, 0.f, 0.f, 0.f};

    for (int kt = 0; kt < 64; ++kt) {
        __syncthreads();  // b0: prev PV-B reads done; region + p free
        {   // stage K tile [64 kv][256 H]
            const __hip_bfloat16* src = Kb + (size_t)(kt * 64 + krow) * Hh + kcb;
            #pragma unroll
            for (int c0 = 0; c0 < 4; ++c0)
                *(uint4*)&region[idx256(krow, kcb + c0 * 64)] = *(const uint4*)&src[c0 * 64];
        }
        __syncthreads();  // b1

        // QK^T: wave's 16 q-rows x 16 kv cols (half)
        f32x4 acc = (f32x4){0.f, 0.f, 0.f, 0.f};
        __builtin_amdgcn_s_setprio(1);
        #pragma unroll
        for (int h = 0; h < 8; ++h) {
            bf16x8 kf = *(const bf16x8*)&region[idx256(half * 16 + lr, h * 32 + lg * 8)];
            acc = MFMA16(qf[h], kf, acc);
        }
        __builtin_amdgcn_s_setprio(0);

        // softmax + fuzzy clamp; attn store (fp32) + P (bf16)
        #pragma unroll
        for (int r = 0; r < 4; ++r) {
            float p = __expf(acc[r]) * inv_l[r];
            float f = fmaxf(fminf(p, 1.0f - p) * (1.0f / 0.3f), 0.0f);
            int row_l = qg * 16 + lg * 4 + r;
            int col_l = half * 16 + lr;
            attn[((size_t)(b * S + q0 + row_l)) * S + kt * 64 + col_l] = f;
            p_lds[idx64(row_l, col_l)] = __float2bfloat16(f);
        }
        __syncthreads();  // b2: K reads done + p_lds ready

        {   // stage VT lower: d rows [0,256), kv cols [kt*64,+64)
            #pragma unroll
            for (int j = 0; j < 4; ++j) {
                int row = j * 64 + vrow;
                *(uint4*)&region[idx64(row, vcb)] =
                    *(const uint4*)&VTb[(size_t)row * S + kt * 64 + vcb];
            }
        }
        __syncthreads();  // b3

        // P fragments (reused for both PV phases)
        bf16x8 pf[2][2];
        #pragma unroll
        for (int qt = 0; qt < 2; ++qt)
            #pragma unroll
            for (int ks = 0; ks < 2; ++ks)
                pf[qt][ks] = *(const bf16x8*)&p_lds[idx64(qt * 16 + lr, ks * 32 + lg * 8)];

        // PV-A: wave w owns d-slice [32w, 32w+32)
        __builtin_amdgcn_s_setprio(1);
        #pragma unroll
        for (int dt = 0; dt < 2; ++dt)
            #pragma unroll
            for (int ks = 0; ks < 2; ++ks) {
                bf16x8 vf = *(const bf16x8*)&region[idx64(w * 32 + dt * 16 + lr, ks * 32 + lg * 8)];
                #pragma unroll
                for (int qt = 0; qt < 2; ++qt)
                    oacc[qt][dt] = MFMA16(pf[qt][ks], vf, oacc[qt][dt]);
            }
        __builtin_amdgcn_s_setprio(0);
        __syncthreads();  // b4: VT-lower reads done

        {   // stage VT upper: d rows [256,512)
            #pragma unroll
            for (int j = 0; j < 4; ++j) {
                int row = j * 64 + vrow;
                *(uint4*)&region[idx64(row, vcb)] =
                    *(const uint4*)&VTb[(size_t)(256 + row) * S + kt * 64 + vcb];
            }
        }
        __syncthreads();  // b5

        // PV-B: wave w owns d-slice [256+32w, +32)
        __builtin_amdgcn_s_setprio(1);
        #pragma unroll
        for (int dt = 0; dt < 2; ++dt)
            #pragma unroll
            for (int ks = 0; ks < 2; ++ks) {
                bf16x8 vf = *(const bf16x8*)&region[idx64(w * 32 + dt * 16 + lr, ks * 32 + lg * 8)];
                #pragma unroll
                for (int qt = 0; qt < 2; ++qt)
                    oacc[qt][dt + 2] = MFMA16(pf[qt][ks], vf, oacc[qt][dt + 2]);
            }
        __builtin_amdgcn_s_setprio(0);
    }

    // epilogue: out[B][S][D] fp32
    #pragma unroll
    for (int qt = 0; qt < 2; ++qt)
        #pragma unroll
        for (int dt = 0; dt < 4; ++dt) {
            int col = (dt < 2 ? 0 : 256) + w * 32 + (dt & 1) * 16 + lr;
            #pragma unroll
            for (int r = 0; r < 4; ++r) {
                int row = q0 + qt * 16 + lg * 4 + r;
                out[((size_t)(b * S + row)) * Dm + col] = oacc[qt][dt][r];
            }
        }
}

// ---------------------------------------------------------------------------
extern "C" void kernel_launch(void* const* d_in, const int* in_sizes, int n_in,
                              void* d_out, int out_size, void* d_ws, size_t ws_size,
                              hipStream_t stream) {
    const float* x  = (const float*)d_in[0];
    const float* Wq = (const float*)d_in[1];
    const float* bq = (const float*)d_in[2];
    const float* Wk = (const float*)d_in[3];
    const float* bk = (const float*)d_in[4];
    const float* Wv = (const float*)d_in[5];
    const float* bv = (const float*)d_in[6];

    float* out  = (float*)d_out;                      // [4,4096,512]
    float* attn = out + (size_t)Bb * S * Dm;          // [4,4096,4096]

    __hip_bfloat16* q_ws  = (__hip_bfloat16*)d_ws;              // [B][S][H]
    __hip_bfloat16* k_ws  = q_ws + (size_t)Bb * S * Hh;         // [B][S][H]
    __hip_bfloat16* vt_ws = k_ws + (size_t)Bb * S * Hh;         // [B][D][S]
    float*          l_ws  = (float*)(vt_ws + (size_t)Bb * Dm * S); // [B][S][2]

    const float scale = 0.0625f;  // 1/sqrt(256)

    proj_kernel<<<dim3(Hh / 64, (Bb * S) / 64), 256, 0, stream>>>(x, Wq, bq, q_ws, Hh, scale, 0);
    proj_kernel<<<dim3(Hh / 64, (Bb * S) / 64), 256, 0, stream>>>(x, Wk, bk, k_ws, Hh, 1.0f, 0);
    proj_kernel<<<dim3(Dm / 64, (Bb * S) / 64), 256, 0, stream>>>(x, Wv, bv, vt_ws, Dm, 1.0f, 1);

    lsum_kernel<<<512, 512, 0, stream>>>(q_ws, k_ws, l_ws);
    pv_kernel<<<512, 512, 0, stream>>>(q_ws, k_ws, vt_ws, l_ws, out, attn);
}